// Round 2
// baseline (537.644 us; speedup 1.0000x reference)
//
#include <hip/hip_runtime.h>

typedef float v2f __attribute__((ext_vector_type(2)));

// ---------------- compile-time PGA(3,0,1) tables ----------------
namespace pga {
// blade order: (),e0,e1,e2,e3,e01,e02,e03,e12,e13,e23,e012,e013,e023,e123,e0123
constexpr int MASKA[16] = {0,1,2,4,8,3,5,9,6,10,12,7,11,13,14,15};
constexpr int IMASK[16] = {0,1,2,5,3,6,8,11,4,7,9,12,10,13,14,15}; // mask -> idx
constexpr int GR[16]    = {0,1,1,1,1,2,2,2,2,2,2,3,3,3,3,4};

constexpr int osign(int a, int b){ // parity of cross inversions of sorted(a)++sorted(b)
  int c = 0;
  for (int j = 0; j < 4; ++j) if ((b>>j)&1)
    for (int i = j+1; i < 4; ++i) if ((a>>i)&1) ++c;
  return (c&1) ? -1 : 1;
}

struct Tab {
  float gpc[16][16]; int gpk[16][16];
  float jnc[16][16]; int jnk[16][16];
};

constexpr Tab build(){
  Tab t{};
  for (int i = 0; i < 16; ++i) for (int j = 0; j < 16; ++j) {
    const int ma = MASKA[i], mb = MASKA[j];
    // geometric product (e0^2 = 0)
    if (ma & mb & 1) { t.gpc[i][j] = 0.0f; t.gpk[i][j] = 0; }
    else { t.gpk[i][j] = IMASK[ma^mb]; t.gpc[i][j] = (float)osign(ma, mb); }
    // join(x,y) = undual(dual(x) ^ dual(y)), right-complement dual
    const int ua = 15^ma, ub = 15^mb;
    if (ua & ub) { t.jnc[i][j] = 0.0f; t.jnk[i][j] = 0; }
    else {
      const int sa = osign(ma, ua), sb = osign(mb, ub);
      const int m  = ua | ub;
      const int tt = osign(ua, ub);
      const int r  = 15^m;
      const int sr = osign(r, m);
      t.jnk[i][j] = IMASK[r];
      t.jnc[i][j] = (float)(sa*sb*tt*sr);
    }
  }
  return t;
}
constexpr Tab TAB = build();
// (src, e0-blade) pairs; src = blade \ e0
constexpr int PS[8] = {0,2,3,4,8,9,10,14};
constexpr int PE[8] = {1,5,6,7,11,12,13,15};
} // namespace pga

// ---------------- helpers ----------------
__device__ __forceinline__ float sel4(float a, float b, float c, float d, int k){
  float lo = (k & 1) ? b : a;
  float hi = (k & 1) ? d : c;
  return (k & 2) ? hi : lo;
}
// cross-quad butterfly adds via DPP quad_perm (VALU pipe, no LDS traffic)
__device__ __forceinline__ float xadd1(float v){
  return v + __int_as_float(__builtin_amdgcn_update_dpp(0, __float_as_int(v), 0xB1, 0xF, 0xF, false)); // [1,0,3,2]
}
__device__ __forceinline__ float xadd2(float v){
  return v + __int_as_float(__builtin_amdgcn_update_dpp(0, __float_as_int(v), 0x4E, 0xF, 0xF, false)); // [2,3,0,1]
}

#define NP 8
#define XS_ROW 36        // blade-row pitch (32 ch + pad4), conflict-analyzed
#define XS_PP  584       // per-position pitch: 16*36 + 8 (de-phases phase-B writes)
#define HS_BASE 4672     // = NP*XS_PP
#define HS_OP   18       // per-channel row: 16 slots + 2 pad (b64-aligned writes)
#define HS_PP   1160     // per-position: 64*18 + 8
#define LDS_FLOATS 13952 // 4672 + 8*1160  (55808 B -> 2 blocks/CU)

// one qi-unrolled equi_linear micro-tile: T_o=2, 8 c (4 v2f pairs), one blade-half
// slot pattern (both halves, after half-1 pair rotation): qi0 -> slots {0,2,4}, qi1-3 -> {1,3,5}
__device__ __forceinline__ void equi_tile(const float* __restrict__ b,
    const v2f (&W)[2][4][6], const int (&offS)[4], const int (&offE)[4],
    v2f (&aS)[2][4], v2f (&aE)[2][4])
{
  #pragma unroll
  for (int qi = 0; qi < 4; ++qi) {
    const int s5 = (qi == 0) ? 0 : 1;
    const int e5 = (qi == 0) ? 2 : 3;
    const int z5 = (qi == 0) ? 4 : 5;
    float4 s0 = *(const float4*)(b + offS[qi]);
    float4 s1 = *(const float4*)(b + offS[qi] + 4);
    float4 t0 = *(const float4*)(b + offE[qi]);
    float4 t1 = *(const float4*)(b + offE[qi] + 4);
    v2f xs2[4] = { {s0.x,s0.y},{s0.z,s0.w},{s1.x,s1.y},{s1.z,s1.w} };
    v2f xe2[4] = { {t0.x,t0.y},{t0.z,t0.w},{t1.x,t1.y},{t1.z,t1.w} };
    #pragma unroll
    for (int cp = 0; cp < 4; ++cp)
      #pragma unroll
      for (int oo = 0; oo < 2; ++oo) {
        aS[oo][qi] += W[oo][cp][s5] * xs2[cp];
        aE[oo][qi] += W[oo][cp][e5] * xe2[cp];
        aE[oo][qi] += W[oo][cp][z5] * xs2[cp];   // e0-wedge map, sign +1
      }
  }
}

__launch_bounds__(256, 2)
__global__ void pga_fused(const float* __restrict__ x, const float* __restrict__ refmv,
                          const float* __restrict__ Wb, const float* __restrict__ Wo,
                          float* __restrict__ out)
{
  __shared__ float lds[LDS_FLOATS];
  const int tid = threadIdx.x;
  const long long pos0 = (long long)blockIdx.x * NP;

  const int cb  = tid & 3;          // c-chunk (8 channels each)
  const int ah  = (tid >> 2) & 1;   // blade-half
  const int ogA = tid >> 3;         // 0..31 ; phase-A o = ogA, ogA+32
  const int ogC = (tid >> 3) & 15;  // 0..15 ; phase-C o = ogC, ogC+16
  const int p2  = tid >> 7;         // phase-C concurrent-position bit

  // per-thread blade rows; half-1 pairs rotated to {(14,15),(8,11),(9,12),(10,13)}
  const int S0t[4] = {0,2,3,4},  S1t[4] = {14,8,9,10};
  const int E0t[4] = {1,5,6,7},  E1t[4] = {15,11,12,13};
  int offS[4], offE[4];
  #pragma unroll
  for (int qi = 0; qi < 4; ++qi) {
    offS[qi] = (ah ? S1t[qi] : S0t[qi]) * XS_ROW;
    offE[qi] = (ah ? E1t[qi] : E0t[qi]) * XS_ROW;
  }
  // weight slot -> w index (per half)
  const int WH0[6] = {0,1,1,2,5,6}, WH1[6] = {3,2,4,3,8,7};
  int W6[6];
  #pragma unroll
  for (int s = 0; s < 6; ++s) W6[s] = ah ? WH1[s] : WH0[s];
  // hs slot offset for this thread's qi=cb pair (permuted slot order m = 2q,2q+1)
  const int mA = ah ? ((cb == 0) ? 14 : (6 + 2*cb)) : 2*cb;

  // ---- phase-A weights: o = ogA, ogA+32 ; c = cb*8 .. +8 (pk over c-pairs)
  v2f WA[2][4][6];
  #pragma unroll
  for (int oo = 0; oo < 2; ++oo) {
    const float* wb = Wb + (size_t)((ogA + oo*32)*32 + cb*8)*9;
    #pragma unroll
    for (int cp = 0; cp < 4; ++cp)
      #pragma unroll
      for (int s = 0; s < 6; ++s)
        WA[oo][cp][s] = (v2f){ wb[(2*cp)*9 + W6[s]], wb[(2*cp+1)*9 + W6[s]] };
  }

  // ---- stage x -> LDS transposed xs[p][blade][36] (2-way max on writes)
  {
    const float4* xg = (const float4*)(x + pos0*512);
    #pragma unroll
    for (int r = 0; r < 4; ++r) {
      int idx = tid + 256*r;           // idx = p*128 + c*4 + aq
      float4 g = xg[idx];
      int p = idx >> 7, c = (idx >> 2) & 31, aq = idx & 3;
      float* b = &lds[p*XS_PP + c];
      b[(aq*4+0)*XS_ROW] = g.x;
      b[(aq*4+1)*XS_ROW] = g.y;
      b[(aq*4+2)*XS_ROW] = g.z;
      b[(aq*4+3)*XS_ROW] = g.w;
    }
  }
  __syncthreads();

  // ---- Phase A: equi_linear(x, W_bil) -> hs   (T_o=2, blade-half split)
  #pragma unroll 1
  for (int p = 0; p < NP; ++p) {
    const float* xb = &lds[p*XS_PP + cb*8];
    v2f aS[2][4], aE[2][4];
    #pragma unroll
    for (int oo = 0; oo < 2; ++oo)
      #pragma unroll
      for (int qi = 0; qi < 4; ++qi) { aS[oo][qi] = (v2f){0.f,0.f}; aE[oo][qi] = (v2f){0.f,0.f}; }
    equi_tile(xb, WA, offS, offE, aS, aE);
    #pragma unroll
    for (int oo = 0; oo < 2; ++oo) {
      float hS[4], hE[4];
      #pragma unroll
      for (int qi = 0; qi < 4; ++qi) {
        hS[qi] = xadd2(xadd1(aS[oo][qi].x + aS[oo][qi].y));  // butterfly over 4 cb lanes
        hE[qi] = xadd2(xadd1(aE[oo][qi].x + aE[oo][qi].y));
      }
      float2 st = { sel4(hS[0],hS[1],hS[2],hS[3],cb), sel4(hE[0],hE[1],hE[2],hE[3],cb) };
      *(float2*)&lds[HS_BASE + p*HS_PP + (ogA + oo*32)*HS_OP + mA] = st;
    }
  }
  __syncthreads();

  // ---- Phase B: per-channel GP / JOIN (wave-uniform half)
  {
    const int half = tid >> 7, pb = (tid >> 4) & 7, cc = tid & 15;
    const float* r0 = &lds[HS_BASE + pb*HS_PP + (half*32 + cc)*HS_OP];
    const float* r1 = r0 + 16*HS_OP;
    float L[16], R[16];
    #pragma unroll
    for (int k = 0; k < 4; ++k) {   // un-permute slots m=2q+{0,1} -> natural blades
      float4 f = *(const float4*)(r0 + 4*k);
      L[pga::PS[2*k]] = f.x; L[pga::PE[2*k]] = f.y; L[pga::PS[2*k+1]] = f.z; L[pga::PE[2*k+1]] = f.w;
      float4 g = *(const float4*)(r1 + 4*k);
      R[pga::PS[2*k]] = g.x; R[pga::PE[2*k]] = g.y; R[pga::PS[2*k+1]] = g.z; R[pga::PE[2*k+1]] = g.w;
    }
    float acc[16];
    #pragma unroll
    for (int k = 0; k < 16; ++k) acc[k] = 0.f;
    if (half == 0) {
      #pragma unroll
      for (int i = 0; i < 16; ++i)
        #pragma unroll
        for (int j = 0; j < 16; ++j)
          if (pga::TAB.gpc[i][j] != 0.0f)
            acc[pga::TAB.gpk[i][j]] = fmaf(pga::TAB.gpc[i][j]*L[i], R[j], acc[pga::TAB.gpk[i][j]]);
    } else {
      #pragma unroll
      for (int i = 0; i < 16; ++i)
        #pragma unroll
        for (int j = 0; j < 16; ++j)
          if (pga::TAB.jnc[i][j] != 0.0f)
            acc[pga::TAB.jnk[i][j]] = fmaf(pga::TAB.jnc[i][j]*L[i], R[j], acc[pga::TAB.jnk[i][j]]);
      const float s = refmv[(pos0 + pb)*16 + 14];
      #pragma unroll
      for (int k = 0; k < 16; ++k) acc[k] *= s;
    }
    // write y transposed into xs region (x is dead): ys[p][a][col], col = half*16+cc
    float* yb = &lds[pb*XS_PP + (half*16 + cc)];
    #pragma unroll
    for (int a = 0; a < 16; ++a) yb[a*XS_ROW] = acc[a];
  }

  // ---- phase-C weights (A-weights dead): o = ogC, ogC+16
  v2f WC[2][4][6];
  #pragma unroll
  for (int oo = 0; oo < 2; ++oo) {
    const float* wo = Wo + (size_t)((ogC + oo*16)*32 + cb*8)*9;
    #pragma unroll
    for (int cp = 0; cp < 4; ++cp)
      #pragma unroll
      for (int s = 0; s < 6; ++s)
        WC[oo][cp][s] = (v2f){ wo[(2*cp)*9 + W6[s]], wo[(2*cp+1)*9 + W6[s]] };
  }
  __syncthreads();

  // ---- Phase C: equi_linear(y, W_out) -> out  (T_o=2, blade-half split, 2 pos concurrent)
  #pragma unroll 1
  for (int it = 0; it < 4; ++it) {
    const int p = it*2 + p2;
    const float* yb = &lds[p*XS_PP + cb*8];
    v2f aS[2][4], aE[2][4];
    #pragma unroll
    for (int oo = 0; oo < 2; ++oo)
      #pragma unroll
      for (int qi = 0; qi < 4; ++qi) { aS[oo][qi] = (v2f){0.f,0.f}; aE[oo][qi] = (v2f){0.f,0.f}; }
    equi_tile(yb, WC, offS, offE, aS, aE);
    #pragma unroll
    for (int oo = 0; oo < 2; ++oo) {
      float hS[4], hE[4];
      #pragma unroll
      for (int qi = 0; qi < 4; ++qi) {
        hS[qi] = xadd2(xadd1(aS[oo][qi].x + aS[oo][qi].y));
        hE[qi] = xadd2(xadd1(aE[oo][qi].x + aE[oo][qi].y));
      }
      // natural-blade-order pair for global store (derived per half/cb)
      float c0 = ah ? sel4(hS[1],hS[3],hE[2],hS[0],cb) : sel4(hS[0],hS[1],hS[3],hE[2],cb);
      float c1 = ah ? sel4(hS[2],hE[1],hE[3],hE[0],cb) : sel4(hE[0],hS[2],hE[1],hE[3],cb);
      *(float2*)&out[(pos0 + p)*512 + (ogC + oo*16)*16 + ah*8 + 2*cb] = (float2){c0, c1};
    }
  }
}

extern "C" void kernel_launch(void* const* d_in, const int* in_sizes, int n_in,
                              void* d_out, int out_size, void* d_ws, size_t ws_size,
                              hipStream_t stream) {
  const float* x  = (const float*)d_in[0];
  const float* rm = (const float*)d_in[1];
  const float* wb = (const float*)d_in[2];
  const float* wo = (const float*)d_in[3];
  float* outp = (float*)d_out;
  const int P = in_sizes[0] / 512;   // B*S positions
  const int blocks = P / NP;         // 8192 for the bench shape
  pga_fused<<<blocks, 256, 0, stream>>>(x, rm, wb, wo, outp);
}